// Round 12
// baseline (149.560 us; speedup 1.0000x reference)
//
#include <hip/hip_runtime.h>

// R22: R20 zero-dup structure x 2 independent WGs per CU. B=4096, L=256,
// H=32, D=2. 512 WGs x 512 threads (8 waves), 8 batches/WG, 2 WGs/CU
// (64KB LDS cap, R17-verified), 4 waves/SIMD total.
// R12 reinterpreted: 2 co-resident WGs interleave to ISSUE-BOUND (787 ~=
// 2x390 issue, chain fully hidden). R20 is chain-exposed (615 = 264 issue +
// 350 naked chain). This kernel keeps R20's minimum-issue step (~110
// cyc/wave: 1 MFMA, 0 extract, 1 cell, 7 trans) and restores issue
// saturation: 4 waves/SIMD x ~110 = ~440 < 615.
// Dup-2 mechanics (8 batches in 16 cols): reads use row m&7 (broadcast,
// free); lanes m>=8 compute duplicate cells and write hbuf rows 8-15
// (never read) -> no branches, no extra instructions.
// Everything else = R20: tile w row i = gate(i&3) of unit 4w+(i>>2), bias
// in MFMA C-in, combined-rcp cell, rotating head MFMA by (t-1)&7, 4-step
// unroll + dword spin prefetch, cvt_pk pack, post ELU/log-softmax.

typedef __attribute__((ext_vector_type(8))) short bf16x8;
typedef __attribute__((ext_vector_type(4))) float f32x4;

#define LOG2E 1.4426950408889634f
#define LN2   0.6931471805599453f

__device__ __forceinline__ float fexp2(float x) { return __builtin_amdgcn_exp2f(x); }
__device__ __forceinline__ float flog2(float x) { return __builtin_amdgcn_logf(x); }
__device__ __forceinline__ float frcp(float x)  { return __builtin_amdgcn_rcpf(x); }

__device__ __forceinline__ float fsig(float x)   { return frcp(1.f + fexp2(-LOG2E * x)); }
__device__ __forceinline__ float ftanh_(float x) { return 1.f - 2.f * frcp(fexp2(2.f * LOG2E * x) + 1.f); }
__device__ __forceinline__ float felu(float x)   { return x > 0.f ? x : fexp2(LOG2E * x) - 1.f; }

__device__ __forceinline__ unsigned short f2bf(float f) {   // RNE f32->bf16
    unsigned u = __builtin_bit_cast(unsigned, f);
    u = (u + 0x7FFFu + ((u >> 16) & 1u)) >> 16;
    return (unsigned short)u;
}

__device__ __forceinline__ unsigned cvtpk_bf16(float a, float b) {
    unsigned r;
    asm("v_cvt_pk_bf16_f32 %0, %1, %2" : "=v"(r) : "v"(a), "v"(b));
    return r;   // lo16 = bf16(a), hi16 = bf16(b), RNE
}

constexpr int Bsz = 4096;

__global__ __launch_bounds__(512, 4) void lstm_r22(
    const int*   __restrict__ x,    // [B, 256]
    const float* __restrict__ Wi,   // [2, 128]
    const float* __restrict__ Wh,   // [32, 128]
    const float* __restrict__ bh,   // [128]
    const float* __restrict__ Wo,   // [32, 2]
    const float* __restrict__ bo,   // [2]
    float*       __restrict__ out)  // [B]
{
    const int tid  = threadIdx.x;
    const int w    = tid >> 6;      // wave 0..7 == gate tile
    const int lane = tid & 63;
    const int m    = lane & 15;     // MFMA column; batch = m&7 (dup 2)
    const int mb   = m & 7;         // batch within WG
    const int oct  = lane >> 4;
    const int b0   = blockIdx.x * 8;

    __shared__ char   spinT[8][260];      // [batch][t] bytes, padded row
    __shared__ float2 Sbuf[256][28];      // logits cols 0..7; cols 8..27 pad
                                          // (indexed array, not DCE-able):
                                          // ~64KB/WG -> exactly 2 WGs/CU
    __shared__ short  hbuf[2][16][40];    // h dbuf, 80B stride; rows 8..15 =
                                          // scratch for dup lanes (never read)
    __shared__ float  red[64][8];

    // ---- stage spins: first 256 threads x 8 bytes (8 rows x 256) ----
    if (tid < 256) {
        const int bl = tid >> 5;          // row 0..7
        const int c8 = (tid & 31) * 8;
        const int4* src = reinterpret_cast<const int4*>(x + (b0 + bl) * 256 + c8);
        const int4 v0 = src[0], v1 = src[1];
        const int p0 = (v0.x & 1) | ((v0.y & 1) << 8) | ((v0.z & 1) << 16) | ((v0.w & 1) << 24);
        const int p1 = (v1.x & 1) | ((v1.y & 1) << 8) | ((v1.z & 1) << 16) | ((v1.w & 1) << 24);
        *reinterpret_cast<int*>(&spinT[bl][c8])     = p0;
        *reinterpret_cast<int*>(&spinT[bl][c8 + 4]) = p1;
    }

    // ---- A-frag: tile w, row m = gate (m&3) of unit 4w + (m>>2) ----
    bf16x8 wfrag;
    {
        const int r = m & 3;
        const float gs = (r == 2) ? 2.f * LOG2E : -LOG2E;
        const int colg = 32 * r + 4 * w + (m >> 2);
#pragma unroll
        for (int j = 0; j < 8; ++j)
            wfrag[j] = (short)f2bf(gs * Wh[(8 * oct + j) * 128 + colg]);
    }
    bf16x8 wfragO;   // head: Wo cols in rows 0,1
#pragma unroll
    for (int j = 0; j < 8; ++j)
        wfragO[j] = (m < 2) ? (short)f2bf(Wo[(8 * oct + j) * 2 + m]) : (short)0;

    // ---- this lane's cell + scaled biases (lanes m>=8 = duplicates) ----
    const int u = 4 * w + oct;
    float bv0[4], bvd[4];
#pragma unroll
    for (int r = 0; r < 4; ++r) {
        const float gs = (r == 2) ? 2.f * LOG2E : -LOG2E;
        const int c0 = 32 * r + u;
        bv0[r] = gs * (bh[c0] + Wi[c0]);
        bvd[r] = gs * (Wi[128 + c0] - Wi[c0]);
    }
    const float bo0 = bo[0], bo1 = bo[1];

    // ---- peel t=0: input zeros, h=c=0 -> gates = bh ----
    // lanes m>=8 write scratch rows 8..15 (identical values, never read)
    float c = fsig(bh[u]) * ftanh_(bh[64 + u]);
    hbuf[0][m][u] = (short)f2bf(fsig(bh[96 + u]) * ftanh_(c));
    __syncthreads();   // spins + h0 visible

    const int wS = __builtin_amdgcn_readfirstlane(w);
    const f32x4 zero4 = { 0.f, 0.f, 0.f, 0.f };

    // one step; rb/wb compile-time at each call site -> static addresses
    auto step = [&](const int t, const int rb, const int wb, const float spf) {
        const bf16x8 hfrag =
            *reinterpret_cast<const bf16x8*>(&hbuf[rb][mb][8 * oct]);

        f32x4 cb;   // bias into MFMA C-in; every slot is this lane's cell
#pragma unroll
        for (int r = 0; r < 4; ++r) cb[r] = fmaf(spf, bvd[r], bv0[r]);

        const f32x4 acc =
            __builtin_amdgcn_mfma_f32_16x16x32_bf16(wfrag, hfrag, cb, 0, 0, 0);

        // cell update (gates = acc directly); e_i=e^{-i}, e_f=e^{-f},
        // e_g=e^{2g}, e_o=e^{-o}; combined reciprocal saves one rcp.
        const float ei = fexp2(acc[0]), ef = fexp2(acc[1]);
        const float eg = fexp2(acc[2]), eo = fexp2(acc[3]);
        const float P = (1.f + ei) * (1.f + eg);
        const float Q = 1.f + ef;
        const float R = frcp(P * Q);
        c = fmaf(P * R, c, (eg - 1.f) * Q * R);   // sig(f)*c + sig(i)*tanh(g)
        const float ec = fexp2(2.f * LOG2E * c);
        const float h  = (ec - 1.f) * frcp((1.f + eo) * (1.f + ec));
        hbuf[wb][m][u] = (short)cvtpk_bf16(h, h);

        // head logits of step t-1: round-robin wave, off critical path
        if (wS == ((t - 1) & 7)) {
            const f32x4 aO =
                __builtin_amdgcn_mfma_f32_16x16x32_bf16(wfragO, hfrag, zero4, 0, 0, 0);
            if (oct == 0 && m < 8) Sbuf[t - 1][m] = make_float2(aO[0], aO[1]);
        }
        __syncthreads();   // h_t visible to all waves
    };

    // 4-step unroll; spins for steps (tb..tb+3) = bytes (tb-1..tb+2), one
    // aligned dword, prefetched a group ahead (tb-1 % 4 == 0 -> aligned).
    unsigned sp4 = *reinterpret_cast<const unsigned*>(&spinT[mb][0]);
    for (int tb = 1; tb < 253; tb += 4) {
        const unsigned sp4n =
            *reinterpret_cast<const unsigned*>(&spinT[mb][tb + 3]);
        step(tb,     0, 1, (float)(sp4 & 0xFFu));
        step(tb + 1, 1, 0, (float)((sp4 >> 8) & 0xFFu));
        step(tb + 2, 0, 1, (float)((sp4 >> 16) & 0xFFu));
        step(tb + 3, 1, 0, (float)(sp4 >> 24));
        sp4 = sp4n;
    }
    // tail steps 253..255 use spin bytes 252..254
    step(253, 0, 1, (float)(sp4 & 0xFFu));
    step(254, 1, 0, (float)((sp4 >> 8) & 0xFFu));
    step(255, 0, 1, (float)((sp4 >> 16) & 0xFFu));

    // ---- tail: head logits of step 255 (h_255 in hbuf[1]) by wave 7 ----
    if (wS == 7) {
        const bf16x8 hfrag = *reinterpret_cast<const bf16x8*>(&hbuf[1][mb][8 * oct]);
        const f32x4 aO =
            __builtin_amdgcn_mfma_f32_16x16x32_bf16(wfragO, hfrag, zero4, 0, 0, 0);
        if (oct == 0 && m < 8) Sbuf[255][m] = make_float2(aO[0], aO[1]);
    }
    __syncthreads();

    // ---- post phase: ELU + log-softmax + sum over t, 64 time-chunks ----
    {
        float lp = 0.f;
        const int bpost = tid & 7;      // batch
        const int tc    = tid >> 3;     // time chunk 0..63
#pragma unroll
        for (int i = 0; i < 4; ++i) {
            const int t = tc * 4 + i;
            const float2 sv = Sbuf[t][bpost];
            const int sp = spinT[bpost][t];
            const float o0 = felu(sv.x + bo0);
            const float o1 = felu(sv.y + bo1);
            const float mx = fmaxf(o0, o1), mn = fminf(o0, o1);
            const float lse = mx + LN2 * flog2(1.f + fexp2(LOG2E * (mn - mx)));
            lp += (sp ? o1 : o0) - lse;
        }
        red[tc][bpost] = lp;
    }
    __syncthreads();
    if (tid < 8) {
        float s = 0.f;
#pragma unroll
        for (int tc2 = 0; tc2 < 64; ++tc2) s += red[tc2][tid];
        out[b0 + tid] = 0.5f * s;
    }
}

extern "C" void kernel_launch(void* const* d_in, const int* in_sizes, int n_in,
                              void* d_out, int out_size, void* d_ws, size_t ws_size,
                              hipStream_t stream) {
    const int*   x  = (const int*)d_in[0];
    const float* Wi = (const float*)d_in[1];
    const float* Wh = (const float*)d_in[2];
    const float* bh = (const float*)d_in[3];
    const float* Wo = (const float*)d_in[4];
    const float* bo = (const float*)d_in[5];
    float* out = (float*)d_out;

    // 512 WGs x 8 waves; ~64KB LDS/WG -> exactly 2 WGs/CU, 4 waves/SIMD
    // from 2 INDEPENDENT WGs -> issue-saturated (R12 behavior) at R20's
    // minimum per-wave issue.
    lstm_r22<<<dim3(Bsz / 8), dim3(512), 0, stream>>>(x, Wi, Wh, bh, Wo, bo, out);
}

// Round 13
// 126.670 us; speedup vs baseline: 1.1807x; 1.1807x over previous
//
#include <hip/hip_runtime.h>

// R23: R20 (best measured: 65.6us dispatch) + head-MFMA hoist. B=4096,
// L=256, H=32, D=2. 256 WGs x 512 threads (8 waves), 16 batches/WG,
// 1 WG/CU, 2 waves/SIMD.
// Final structure map (R10-R22): issue/SIMD floor ~260cy (= 512 cells/CU
// of 7-transcendental cell math; R20 attains it); stall floor ~350cy
// (ds_read 120 + MFMA ~30 + trans chain ~130 + barrier skew), invariant
// under all topologies (1/2 WGs per CU), priorities, seeds, conflict fixes.
// Cross-WG hiding never materializes (phase-lock: R12/R17/R22).
// R23's one change vs R20: the rotating head-logit MFMA is ISSUED right
// after the gates MFMA (latency hides under the ~130cy cell update) instead
// of sitting fully exposed after the h-write; only the 2 Sbuf stores remain
// near the barrier. Everything else identical to R20:
//  - tile w row i = gate (i&3) of unit 4w+(i>>2); 16 DISTINCT batch cols;
//    lane (m,oct) acc[r] IS gate r of cell u=4w+oct, batch m (zero dup,
//    zero extract, 1 MFMA + 1 cell per lane-step).
//  - bias+Wi*spin in MFMA C-in (every slot used).
//  - h: ds_write_b16 -> 1 barrier -> ds_read_b128 (hbuf 80B stride).
//  - combined-rcp cell (7 trans), 4-step unroll + dword spin prefetch,
//    cvt_pk h pack, post-loop ELU/log-softmax.

typedef __attribute__((ext_vector_type(8))) short bf16x8;
typedef __attribute__((ext_vector_type(4))) float f32x4;

#define LOG2E 1.4426950408889634f
#define LN2   0.6931471805599453f

__device__ __forceinline__ float fexp2(float x) { return __builtin_amdgcn_exp2f(x); }
__device__ __forceinline__ float flog2(float x) { return __builtin_amdgcn_logf(x); }
__device__ __forceinline__ float frcp(float x)  { return __builtin_amdgcn_rcpf(x); }

__device__ __forceinline__ float fsig(float x)   { return frcp(1.f + fexp2(-LOG2E * x)); }
__device__ __forceinline__ float ftanh_(float x) { return 1.f - 2.f * frcp(fexp2(2.f * LOG2E * x) + 1.f); }
__device__ __forceinline__ float felu(float x)   { return x > 0.f ? x : fexp2(LOG2E * x) - 1.f; }

__device__ __forceinline__ unsigned short f2bf(float f) {   // RNE f32->bf16
    unsigned u = __builtin_bit_cast(unsigned, f);
    u = (u + 0x7FFFu + ((u >> 16) & 1u)) >> 16;
    return (unsigned short)u;
}

__device__ __forceinline__ unsigned cvtpk_bf16(float a, float b) {
    unsigned r;
    asm("v_cvt_pk_bf16_f32 %0, %1, %2" : "=v"(r) : "v"(a), "v"(b));
    return r;   // lo16 = bf16(a), hi16 = bf16(b), RNE
}

constexpr int Bsz = 4096;

__global__ __launch_bounds__(512, 1) void lstm_r23(
    const int*   __restrict__ x,    // [B, 256]
    const float* __restrict__ Wi,   // [2, 128]
    const float* __restrict__ Wh,   // [32, 128]
    const float* __restrict__ bh,   // [128]
    const float* __restrict__ Wo,   // [32, 2]
    const float* __restrict__ bo,   // [2]
    float*       __restrict__ out)  // [B]
{
    const int tid  = threadIdx.x;
    const int w    = tid >> 6;      // wave 0..7 == gate tile
    const int lane = tid & 63;
    const int m    = lane & 15;     // MFMA column == batch (16, no dup)
    const int oct  = lane >> 4;
    const int b0   = blockIdx.x * 16;

    __shared__ char   spinT[16][260];     // [batch][t] bytes, padded row
    __shared__ float2 Sbuf[256][16];      // raw logits (S0,S1) per (t,batch)
    __shared__ short  hbuf[2][16][40];    // h dbuf, row stride 80 B
    __shared__ float  red[32][16];

    // ---- stage spins: 512 threads x 8 bytes (16 rows x 256) ----
    {
        const int bl = tid >> 5;          // row 0..15
        const int c8 = (tid & 31) * 8;
        const int4* src = reinterpret_cast<const int4*>(x + (b0 + bl) * 256 + c8);
        const int4 v0 = src[0], v1 = src[1];
        const int p0 = (v0.x & 1) | ((v0.y & 1) << 8) | ((v0.z & 1) << 16) | ((v0.w & 1) << 24);
        const int p1 = (v1.x & 1) | ((v1.y & 1) << 8) | ((v1.z & 1) << 16) | ((v1.w & 1) << 24);
        *reinterpret_cast<int*>(&spinT[bl][c8])     = p0;
        *reinterpret_cast<int*>(&spinT[bl][c8 + 4]) = p1;
    }

    // ---- A-frag: tile w, row m = gate (m&3) of unit 4w + (m>>2) ----
    bf16x8 wfrag;
    {
        const int r = m & 3;
        const float gs = (r == 2) ? 2.f * LOG2E : -LOG2E;
        const int colg = 32 * r + 4 * w + (m >> 2);
#pragma unroll
        for (int j = 0; j < 8; ++j)
            wfrag[j] = (short)f2bf(gs * Wh[(8 * oct + j) * 128 + colg]);
    }
    bf16x8 wfragO;   // head: Wo cols in rows 0,1
#pragma unroll
    for (int j = 0; j < 8; ++j)
        wfragO[j] = (m < 2) ? (short)f2bf(Wo[(8 * oct + j) * 2 + m]) : (short)0;

    // ---- this lane's cell + scaled biases ----
    const int u = 4 * w + oct;
    float bv0[4], bvd[4];
#pragma unroll
    for (int r = 0; r < 4; ++r) {
        const float gs = (r == 2) ? 2.f * LOG2E : -LOG2E;
        const int c0 = 32 * r + u;
        bv0[r] = gs * (bh[c0] + Wi[c0]);
        bvd[r] = gs * (Wi[128 + c0] - Wi[c0]);
    }
    const float bo0 = bo[0], bo1 = bo[1];

    // ---- peel t=0: input zeros, h=c=0 -> gates = bh ----
    float c = fsig(bh[u]) * ftanh_(bh[64 + u]);
    hbuf[0][m][u] = (short)f2bf(fsig(bh[96 + u]) * ftanh_(c));
    __syncthreads();   // spins + h0 visible

    const int wS = __builtin_amdgcn_readfirstlane(w);
    const f32x4 zero4 = { 0.f, 0.f, 0.f, 0.f };

    // one step; rb/wb compile-time at each call site -> static addresses
    auto step = [&](const int t, const int rb, const int wb, const float spf) {
        const bf16x8 hfrag =
            *reinterpret_cast<const bf16x8*>(&hbuf[rb][m][8 * oct]);

        f32x4 cb;   // bias into MFMA C-in; every slot is this lane's cell
#pragma unroll
        for (int r = 0; r < 4; ++r) cb[r] = fmaf(spf, bvd[r], bv0[r]);

        const f32x4 acc =
            __builtin_amdgcn_mfma_f32_16x16x32_bf16(wfrag, hfrag, cb, 0, 0, 0);

        // head MFMA of step t-1: ISSUE here (latency hides under the cell
        // update); stores deferred to after the h-write.
        const bool isHead = (wS == ((t - 1) & 7));
        f32x4 aO = zero4;
        if (isHead)
            aO = __builtin_amdgcn_mfma_f32_16x16x32_bf16(wfragO, hfrag, zero4, 0, 0, 0);

        // cell update (gates = acc directly); e_i=e^{-i}, e_f=e^{-f},
        // e_g=e^{2g}, e_o=e^{-o}; combined reciprocal saves one rcp.
        const float ei = fexp2(acc[0]), ef = fexp2(acc[1]);
        const float eg = fexp2(acc[2]), eo = fexp2(acc[3]);
        const float P = (1.f + ei) * (1.f + eg);
        const float Q = 1.f + ef;
        const float R = frcp(P * Q);
        c = fmaf(P * R, c, (eg - 1.f) * Q * R);   // sig(f)*c + sig(i)*tanh(g)
        const float ec = fexp2(2.f * LOG2E * c);
        const float h  = (ec - 1.f) * frcp((1.f + eo) * (1.f + ec));
        hbuf[wb][m][u] = (short)cvtpk_bf16(h, h);

        if (isHead && oct == 0)
            Sbuf[t - 1][m] = make_float2(aO[0], aO[1]);
        __syncthreads();   // h_t visible to all waves
    };

    // 4-step unroll; spins for steps (tb..tb+3) = bytes (tb-1..tb+2), one
    // aligned dword, prefetched a group ahead (tb-1 % 4 == 0 -> aligned).
    unsigned sp4 = *reinterpret_cast<const unsigned*>(&spinT[m][0]);
    for (int tb = 1; tb < 253; tb += 4) {
        const unsigned sp4n =
            *reinterpret_cast<const unsigned*>(&spinT[m][tb + 3]);
        step(tb,     0, 1, (float)(sp4 & 0xFFu));
        step(tb + 1, 1, 0, (float)((sp4 >> 8) & 0xFFu));
        step(tb + 2, 0, 1, (float)((sp4 >> 16) & 0xFFu));
        step(tb + 3, 1, 0, (float)(sp4 >> 24));
        sp4 = sp4n;
    }
    // tail steps 253..255 use spin bytes 252..254
    step(253, 0, 1, (float)(sp4 & 0xFFu));
    step(254, 1, 0, (float)((sp4 >> 8) & 0xFFu));
    step(255, 0, 1, (float)((sp4 >> 16) & 0xFFu));

    // ---- tail: head logits of step 255 (h_255 in hbuf[1]) by wave 7 ----
    if (wS == 7) {
        const bf16x8 hfrag = *reinterpret_cast<const bf16x8*>(&hbuf[1][m][8 * oct]);
        const f32x4 aO =
            __builtin_amdgcn_mfma_f32_16x16x32_bf16(wfragO, hfrag, zero4, 0, 0, 0);
        if (oct == 0) Sbuf[255][m] = make_float2(aO[0], aO[1]);
    }
    __syncthreads();

    // ---- post phase: ELU + log-softmax + sum over t, 32 time-chunks ----
    {
        float lp = 0.f;
        const int bpost = tid & 15;     // batch
        const int tc    = tid >> 4;     // time chunk 0..31
#pragma unroll
        for (int i = 0; i < 8; ++i) {
            const int t = tc * 8 + i;
            const float2 sv = Sbuf[t][bpost];
            const int sp = spinT[bpost][t];
            const float o0 = felu(sv.x + bo0);
            const float o1 = felu(sv.y + bo1);
            const float mx = fmaxf(o0, o1), mn = fminf(o0, o1);
            const float lse = mx + LN2 * flog2(1.f + fexp2(LOG2E * (mn - mx)));
            lp += (sp ? o1 : o0) - lse;
        }
        red[tc][bpost] = lp;
    }
    __syncthreads();
    if (tid < 16) {
        float s = 0.f;
#pragma unroll
        for (int tc2 = 0; tc2 < 32; ++tc2) s += red[tc2][tid];
        out[b0 + tid] = 0.5f * s;
    }
}

extern "C" void kernel_launch(void* const* d_in, const int* in_sizes, int n_in,
                              void* d_out, int out_size, void* d_ws, size_t ws_size,
                              hipStream_t stream) {
    const int*   x  = (const int*)d_in[0];
    const float* Wi = (const float*)d_in[1];
    const float* Wh = (const float*)d_in[2];
    const float* bh = (const float*)d_in[3];
    const float* Wo = (const float*)d_in[4];
    const float* bo = (const float*)d_in[5];
    float* out = (float*)d_out;

    // 256 WGs = 1 per CU; 8 waves/WG -> 2 waves per SIMD, minimum-issue
    // zero-dup layout (R20 structure, best measured).
    lstm_r23<<<dim3(Bsz / 16), dim3(512), 0, stream>>>(x, Wi, Wh, bh, Wo, bo, out);
}

// Round 14
// 120.486 us; speedup vs baseline: 1.2413x; 1.0513x over previous
//
#include <hip/hip_runtime.h>

// R24 == R20 (best measured: 65.6us dispatch, 120.6us bench). TERMINAL.
// B=4096, L=256, H=32, D=2. 256 WGs x 512 threads (8 waves), 16 batches/WG,
// 1 WG/CU, 2 waves/SIMD.
// Session conclusion (R10-R23): this is the floor of the design space.
//  - step = issue/SIMD + exchange chain. Issue floor ~264cy/SIMD = 512
//    cells/CU x 7-transcendental cell math at zero duplication (this
//    kernel: 1 MFMA, 0 extract ops, 1 cell per lane-step). Chain floor
//    ~350cy = ds_write -> barrier -> ds_read(~120) -> MFMA -> trans
//    dependency(~130); invariant under every tested topology (2x4w, 2x8w,
//    wave-autonomous crossbar, anti-phase split), scheduling hint
//    (s_sleep seed, s_setprio, dedicated head wave, head-MFMA hoist),
//    and LDS fix (conflict-free 88B stride: conflicts 3.15M -> 16K, time
//    unchanged -> off the wall). All deviations measured +7..+90%.
//  - NOT a counter roofline: HBM 0.4%, MfmaUtil 5%, VALUBusy 43% -- a
//    serial recurrence's 256 mandatory all-to-all h-exchanges serialize.
// Layout: tile w row i = gate (i&3) of unit 4w+(i>>2); B-cols = 16
// DISTINCT batches. Lane (m,oct) of wave w: acc[r] IS gate r of cell
// u=4w+oct, batch m; bias+Wi*spin prefolded into the MFMA C operand
// (every slot used). h: ds_write_b16 -> 1 barrier -> ds_read_b128
// (hbuf 80B stride). Combined-rcp cell (7 trans), rotating head MFMA by
// (t-1)&7, 4-step unroll + dword spin prefetch, cvt_pk h pack, post-loop
// ELU/log-softmax.

typedef __attribute__((ext_vector_type(8))) short bf16x8;
typedef __attribute__((ext_vector_type(4))) float f32x4;

#define LOG2E 1.4426950408889634f
#define LN2   0.6931471805599453f

__device__ __forceinline__ float fexp2(float x) { return __builtin_amdgcn_exp2f(x); }
__device__ __forceinline__ float flog2(float x) { return __builtin_amdgcn_logf(x); }
__device__ __forceinline__ float frcp(float x)  { return __builtin_amdgcn_rcpf(x); }

__device__ __forceinline__ float fsig(float x)   { return frcp(1.f + fexp2(-LOG2E * x)); }
__device__ __forceinline__ float ftanh_(float x) { return 1.f - 2.f * frcp(fexp2(2.f * LOG2E * x) + 1.f); }
__device__ __forceinline__ float felu(float x)   { return x > 0.f ? x : fexp2(LOG2E * x) - 1.f; }

__device__ __forceinline__ unsigned short f2bf(float f) {   // RNE f32->bf16
    unsigned u = __builtin_bit_cast(unsigned, f);
    u = (u + 0x7FFFu + ((u >> 16) & 1u)) >> 16;
    return (unsigned short)u;
}

__device__ __forceinline__ unsigned cvtpk_bf16(float a, float b) {
    unsigned r;
    asm("v_cvt_pk_bf16_f32 %0, %1, %2" : "=v"(r) : "v"(a), "v"(b));
    return r;   // lo16 = bf16(a), hi16 = bf16(b), RNE
}

constexpr int Bsz = 4096;

__global__ __launch_bounds__(512, 1) void lstm_r24(
    const int*   __restrict__ x,    // [B, 256]
    const float* __restrict__ Wi,   // [2, 128]
    const float* __restrict__ Wh,   // [32, 128]
    const float* __restrict__ bh,   // [128]
    const float* __restrict__ Wo,   // [32, 2]
    const float* __restrict__ bo,   // [2]
    float*       __restrict__ out)  // [B]
{
    const int tid  = threadIdx.x;
    const int w    = tid >> 6;      // wave 0..7 == gate tile
    const int lane = tid & 63;
    const int m    = lane & 15;     // MFMA column == batch (16, no dup)
    const int oct  = lane >> 4;
    const int b0   = blockIdx.x * 16;

    __shared__ char   spinT[16][260];     // [batch][t] bytes, padded row
    __shared__ float2 Sbuf[256][16];      // raw logits (S0,S1) per (t,batch)
    __shared__ short  hbuf[2][16][40];    // h dbuf, row stride 80 B
    __shared__ float  red[32][16];

    // ---- stage spins: 512 threads x 8 bytes (16 rows x 256) ----
    {
        const int bl = tid >> 5;          // row 0..15
        const int c8 = (tid & 31) * 8;
        const int4* src = reinterpret_cast<const int4*>(x + (b0 + bl) * 256 + c8);
        const int4 v0 = src[0], v1 = src[1];
        const int p0 = (v0.x & 1) | ((v0.y & 1) << 8) | ((v0.z & 1) << 16) | ((v0.w & 1) << 24);
        const int p1 = (v1.x & 1) | ((v1.y & 1) << 8) | ((v1.z & 1) << 16) | ((v1.w & 1) << 24);
        *reinterpret_cast<int*>(&spinT[bl][c8])     = p0;
        *reinterpret_cast<int*>(&spinT[bl][c8 + 4]) = p1;
    }

    // ---- A-frag: tile w, row m = gate (m&3) of unit 4w + (m>>2) ----
    bf16x8 wfrag;
    {
        const int r = m & 3;
        const float gs = (r == 2) ? 2.f * LOG2E : -LOG2E;
        const int colg = 32 * r + 4 * w + (m >> 2);
#pragma unroll
        for (int j = 0; j < 8; ++j)
            wfrag[j] = (short)f2bf(gs * Wh[(8 * oct + j) * 128 + colg]);
    }
    bf16x8 wfragO;   // head: Wo cols in rows 0,1
#pragma unroll
    for (int j = 0; j < 8; ++j)
        wfragO[j] = (m < 2) ? (short)f2bf(Wo[(8 * oct + j) * 2 + m]) : (short)0;

    // ---- this lane's cell + scaled biases ----
    const int u = 4 * w + oct;
    float bv0[4], bvd[4];
#pragma unroll
    for (int r = 0; r < 4; ++r) {
        const float gs = (r == 2) ? 2.f * LOG2E : -LOG2E;
        const int c0 = 32 * r + u;
        bv0[r] = gs * (bh[c0] + Wi[c0]);
        bvd[r] = gs * (Wi[128 + c0] - Wi[c0]);
    }
    const float bo0 = bo[0], bo1 = bo[1];

    // ---- peel t=0: input zeros, h=c=0 -> gates = bh ----
    float c = fsig(bh[u]) * ftanh_(bh[64 + u]);
    hbuf[0][m][u] = (short)f2bf(fsig(bh[96 + u]) * ftanh_(c));
    __syncthreads();   // spins + h0 visible

    const int wS = __builtin_amdgcn_readfirstlane(w);
    const f32x4 zero4 = { 0.f, 0.f, 0.f, 0.f };

    // one step; rb/wb compile-time at each call site -> static addresses
    auto step = [&](const int t, const int rb, const int wb, const float spf) {
        const bf16x8 hfrag =
            *reinterpret_cast<const bf16x8*>(&hbuf[rb][m][8 * oct]);

        f32x4 cb;   // bias into MFMA C-in; every slot is this lane's cell
#pragma unroll
        for (int r = 0; r < 4; ++r) cb[r] = fmaf(spf, bvd[r], bv0[r]);

        const f32x4 acc =
            __builtin_amdgcn_mfma_f32_16x16x32_bf16(wfrag, hfrag, cb, 0, 0, 0);

        // cell update (gates = acc directly); e_i=e^{-i}, e_f=e^{-f},
        // e_g=e^{2g}, e_o=e^{-o}; combined reciprocal saves one rcp.
        const float ei = fexp2(acc[0]), ef = fexp2(acc[1]);
        const float eg = fexp2(acc[2]), eo = fexp2(acc[3]);
        const float P = (1.f + ei) * (1.f + eg);
        const float Q = 1.f + ef;
        const float R = frcp(P * Q);
        c = fmaf(P * R, c, (eg - 1.f) * Q * R);   // sig(f)*c + sig(i)*tanh(g)
        const float ec = fexp2(2.f * LOG2E * c);
        const float h  = (ec - 1.f) * frcp((1.f + eo) * (1.f + ec));
        hbuf[wb][m][u] = (short)cvtpk_bf16(h, h);

        // head logits of step t-1: round-robin wave, off critical path
        if (wS == ((t - 1) & 7)) {
            const f32x4 aO =
                __builtin_amdgcn_mfma_f32_16x16x32_bf16(wfragO, hfrag, zero4, 0, 0, 0);
            if (oct == 0) Sbuf[t - 1][m] = make_float2(aO[0], aO[1]);
        }
        __syncthreads();   // h_t visible to all waves
    };

    // 4-step unroll; spins for steps (tb..tb+3) = bytes (tb-1..tb+2), one
    // aligned dword, prefetched a group ahead (tb-1 % 4 == 0 -> aligned).
    unsigned sp4 = *reinterpret_cast<const unsigned*>(&spinT[m][0]);
    for (int tb = 1; tb < 253; tb += 4) {
        const unsigned sp4n =
            *reinterpret_cast<const unsigned*>(&spinT[m][tb + 3]);
        step(tb,     0, 1, (float)(sp4 & 0xFFu));
        step(tb + 1, 1, 0, (float)((sp4 >> 8) & 0xFFu));
        step(tb + 2, 0, 1, (float)((sp4 >> 16) & 0xFFu));
        step(tb + 3, 1, 0, (float)(sp4 >> 24));
        sp4 = sp4n;
    }
    // tail steps 253..255 use spin bytes 252..254
    step(253, 0, 1, (float)(sp4 & 0xFFu));
    step(254, 1, 0, (float)((sp4 >> 8) & 0xFFu));
    step(255, 0, 1, (float)((sp4 >> 16) & 0xFFu));

    // ---- tail: head logits of step 255 (h_255 in hbuf[1]) by wave 7 ----
    if (wS == 7) {
        const bf16x8 hfrag = *reinterpret_cast<const bf16x8*>(&hbuf[1][m][8 * oct]);
        const f32x4 aO =
            __builtin_amdgcn_mfma_f32_16x16x32_bf16(wfragO, hfrag, zero4, 0, 0, 0);
        if (oct == 0) Sbuf[255][m] = make_float2(aO[0], aO[1]);
    }
    __syncthreads();

    // ---- post phase: ELU + log-softmax + sum over t, 32 time-chunks ----
    {
        float lp = 0.f;
        const int bpost = tid & 15;     // batch
        const int tc    = tid >> 4;     // time chunk 0..31
#pragma unroll
        for (int i = 0; i < 8; ++i) {
            const int t = tc * 8 + i;
            const float2 sv = Sbuf[t][bpost];
            const int sp = spinT[bpost][t];
            const float o0 = felu(sv.x + bo0);
            const float o1 = felu(sv.y + bo1);
            const float mx = fmaxf(o0, o1), mn = fminf(o0, o1);
            const float lse = mx + LN2 * flog2(1.f + fexp2(LOG2E * (mn - mx)));
            lp += (sp ? o1 : o0) - lse;
        }
        red[tc][bpost] = lp;
    }
    __syncthreads();
    if (tid < 16) {
        float s = 0.f;
#pragma unroll
        for (int tc2 = 0; tc2 < 32; ++tc2) s += red[tc2][tid];
        out[b0 + tid] = 0.5f * s;
    }
}

extern "C" void kernel_launch(void* const* d_in, const int* in_sizes, int n_in,
                              void* d_out, int out_size, void* d_ws, size_t ws_size,
                              hipStream_t stream) {
    const int*   x  = (const int*)d_in[0];
    const float* Wi = (const float*)d_in[1];
    const float* Wh = (const float*)d_in[2];
    const float* bh = (const float*)d_in[3];
    const float* Wo = (const float*)d_in[4];
    const float* bo = (const float*)d_in[5];
    float* out = (float*)d_out;

    // 256 WGs = 1 per CU; 8 waves/WG -> 2 waves per SIMD, minimum-issue
    // zero-dup layout. Best measured configuration of the session.
    lstm_r24<<<dim3(Bsz / 16), dim3(512), 0, stream>>>(x, Wi, Wh, bh, Wo, bo, out);
}